// Round 12
// baseline (1072.846 us; speedup 1.0000x reference)
//
#include <hip/hip_runtime.h>
#include <hip/hip_bf16.h>

#define BB 8
#define CC 256
#define HH 128
#define WW 128
#define KS 9
#define NPIX (BB*HH*WW)   // 131072
#define KDIM (4*CC)       // 1024

typedef __attribute__((ext_vector_type(8))) short bf16x8;
typedef __attribute__((ext_vector_type(4))) float f32x4;

static __device__ __forceinline__ unsigned short f2bf(float f) {
  union { float f; unsigned u; } v; v.f = f;
  unsigned r = v.u + 0x7FFF + ((v.u >> 16) & 1);   // RNE
  return (unsigned short)(r >> 16);
}

// ---------------------------------------------------------------------------
// Prep A': A'[o][k'] bf16, k' = c*4 + t, from wproj[o][t*256 + c] (fp32)
// ---------------------------------------------------------------------------
__global__ void prep_kernel(const float* __restrict__ wproj,
                            unsigned short* __restrict__ Ap) {
  int idx = blockIdx.x * 256 + threadIdx.x;    // 0 .. 262143
  int o  = idx >> 10;
  int kp = idx & 1023;
  int c  = kp >> 2;
  int t  = kp & 3;
  Ap[idx] = f2bf(wproj[o * 1024 + t * 256 + c]);
}

// ---------------------------------------------------------------------------
// Prep W: wt2[c][cv*9+k] f32 (per-channel contiguous 36-float record)
// ---------------------------------------------------------------------------
__global__ void wprep_kernel(const float* __restrict__ wh1,
                             const float* __restrict__ wh2,
                             const float* __restrict__ wv1,
                             const float* __restrict__ wv2,
                             float* __restrict__ wt2) {
  int idx = blockIdx.x * 256 + threadIdx.x;    // 0..9215
  int c = idx / 36;
  int q = idx - c * 36;
  int cv = q / 9, k = q - cv * 9;
  const float* src = (cv == 0) ? wh1 : (cv == 1) ? wh2 : (cv == 2) ? wv1 : wv2;
  wt2[idx] = src[c * KS + k];
}

// ---------------------------------------------------------------------------
// Fused conv+GEMM v2: NCHW-direct. Block = (b,h) row, 512 thr.
// K-loop cg=0..15 (16 ch = 64 k'). Thread (tc = tid&15 -> channel,
// wseg = tid>>4 -> 4 w's). Conv reads x fp32 straight from global
// (L1/L2-hot; 12 vector loads/thread/cg), weights reg-cached from LDS Ws.
// B-tile ds_write XOR-swizzled (verified pair from r9). No transpose,
// no zero-init, no x staging. LDS = Ws 36.9K + Bs 16.4K = 53.2 KB.
// ---------------------------------------------------------------------------
__global__ __launch_bounds__(512, 4)
void fused_kernel(const unsigned short* __restrict__ Ap,
                  const float* __restrict__ x,
                  const float* __restrict__ wt2,
                  float* __restrict__ out) {
  __shared__ __align__(16) float Ws[256 * 36];   // 36864 B
  __shared__ __align__(16) short Bs[128 * 64];   // 16384 B

  int bid = blockIdx.x;
  int pt  = (bid & 7) * 128 + (bid >> 3);   // image -> XCD, h-contiguous
  int b   = pt >> 7, h = pt & 127;
  int tid = threadIdx.x;
  int lane = tid & 63;
  int wv  = tid >> 6;
  int om  = wv & 3, pn = wv >> 2;
  int l15 = lane & 15, kseg = lane >> 4;

  int tc   = tid & 15;          // channel-in-group
  int wseg = tid >> 4;          // 0..31
  int w0   = wseg * 4;

  // one-time: stage weight records into LDS (f32, coalesced float4)
  {
    const float4* srcw = (const float4*)wt2;
    float4* dstw = (float4*)Ws;
    for (int i = tid; i < 2304; i += 512) dstw[i] = srcw[i];
  }
  __syncthreads();

  const float* xb = x + ((size_t)b << 22);    // b*256*16384
  const short* A  = (const short*)Ap;

  f32x4 acc[4][4] = {};

  for (int cg = 0; cg < 16; ++cg) {
    int c = cg * 16 + tc;
    const float* xc = xb + ((size_t)c << 14);

    // weights for this channel: 9 x ds_read_b128 -> 36 f32
    float W[36];
#pragma unroll
    for (int i = 0; i < 9; ++i) {
      float4 v = *(const float4*)&Ws[c * 36 + i * 4];
      W[i*4+0] = v.x; W[i*4+1] = v.y; W[i*4+2] = v.z; W[i*4+3] = v.w;
    }

    // horizontal taps w0-4 .. w0+7 : 3 aligned float4, range-masked
    float xh[12];
    {
      const float* xrow = xc + h * WW;
#pragma unroll
      for (int sgi = 0; sgi < 3; ++sgi) {
        int wi = w0 - 4 + sgi * 4;
        float4 v;
        if (wi >= 0 && wi <= WW - 4) v = *(const float4*)(xrow + wi);
        else v = make_float4(0.f, 0.f, 0.f, 0.f);
        xh[sgi*4+0] = v.x; xh[sgi*4+1] = v.y;
        xh[sgi*4+2] = v.z; xh[sgi*4+3] = v.w;
      }
    }

    // conv: accumulate per output w (j-outer keeps xv live-range = 1 float4)
    float s1[4] = {0.f,0.f,0.f,0.f}, s2[4] = {0.f,0.f,0.f,0.f};
    float s3[4] = {0.f,0.f,0.f,0.f}, s4[4] = {0.f,0.f,0.f,0.f};
#pragma unroll
    for (int j = 0; j < KS; ++j) {
      int r = h - 4 + j;                       // block-uniform predicate
      float4 vj;
      if (r >= 0 && r < HH) vj = *(const float4*)(xc + r * WW + w0);
      else vj = make_float4(0.f, 0.f, 0.f, 0.f);
      float wj1 = W[j], wj2 = W[9+j], wj3 = W[18+j], wj4 = W[27+j];
#pragma unroll
      for (int dw = 0; dw < 4; ++dw) {
        float a = xh[dw + j];
        float v = (dw == 0) ? vj.x : (dw == 1) ? vj.y : (dw == 2) ? vj.z : vj.w;
        s1[dw] = fmaf(a, wj1, s1[dw]);
        s2[dw] = fmaf(a, wj2, s2[dw]);
        s3[dw] = fmaf(v, wj3, s3[dw]);
        s4[dw] = fmaf(v, wj4, s4[dw]);
      }
    }
#pragma unroll
    for (int dw = 0; dw < 4; ++dw) {
      int w = w0 + dw;
      unsigned u0 = (unsigned)f2bf(s1[dw]) | ((unsigned)f2bf(s2[dw]) << 16);
      unsigned u1 = (unsigned)f2bf(s3[dw]) | ((unsigned)f2bf(s4[dw]) << 16);
      int byt = (w * 128 + tc * 8) ^ ((w & 7) << 4);   // verified swizzle (r9)
      *(uint2*)((char*)Bs + byt) = make_uint2(u0, u1);
    }
    __syncthreads();

    // MFMA over this cg's K=64
#pragma unroll
    for (int kk = 0; kk < 2; ++kk) {
      bf16x8 af[4], bfr[4];
      int kg = cg * 64 + kk * 32 + kseg * 8;
#pragma unroll
      for (int m = 0; m < 4; ++m)
        af[m] = *(const bf16x8*)(A + (size_t)(om * 64 + m * 16 + l15) * KDIM + kg);
#pragma unroll
      for (int n = 0; n < 4; ++n) {
        int row = pn * 64 + n * 16 + l15;
        int byt = (row * 128 + kk * 64 + kseg * 16) ^ ((row & 7) << 4);
        bfr[n] = *(const bf16x8*)((const char*)Bs + byt);
      }
#pragma unroll
      for (int m = 0; m < 4; ++m)
#pragma unroll
        for (int n = 0; n < 4; ++n)
          acc[m][n] = __builtin_amdgcn_mfma_f32_16x16x32_bf16(af[m], bfr[n],
                                                              acc[m][n], 0, 0, 0);
    }
    __syncthreads();
  }

  // epilogue: LDS-restaged coalesced stores (512B rows); reuse Ws as f32 buf
  float* Ls = (float*)Ws;            // 32*132*4 = 16896 B <= 36864
  const int LP = 132;
  int er = tid >> 4;                 // 0..31
  int ec = (tid & 15) * 8;           // 0..120
  size_t obase = ((size_t)(b * 256) << 14) + (h << 7);

#pragma unroll
  for (int oc = 0; oc < 8; ++oc) {
    __syncthreads();
    if (om == (oc >> 1)) {
      int mb = (oc & 1) * 2;
#pragma unroll
      for (int mm = 0; mm < 2; ++mm) {
#pragma unroll
        for (int n = 0; n < 4; ++n) {
#pragma unroll
          for (int r = 0; r < 4; ++r) {
            int row = mm * 16 + kseg * 4 + r;          // 0..31
            int col = pn * 64 + n * 16 + l15;          // 0..127
            Ls[row * LP + col] = acc[mb + mm][n][r];
          }
        }
      }
    }
    __syncthreads();
    float4 v0 = *(const float4*)&Ls[er * LP + ec];
    float4 v1 = *(const float4*)&Ls[er * LP + ec + 4];
    size_t oaddr = obase + ((size_t)(oc * 32 + er) << 14) + ec;
    *(float4*)&out[oaddr] = make_float4(fmaxf(v0.x, 0.f), fmaxf(v0.y, 0.f),
                                        fmaxf(v0.z, 0.f), fmaxf(v0.w, 0.f));
    *(float4*)&out[oaddr + 4] = make_float4(fmaxf(v1.x, 0.f), fmaxf(v1.y, 0.f),
                                            fmaxf(v1.z, 0.f), fmaxf(v1.w, 0.f));
  }
}

extern "C" void kernel_launch(void* const* d_in, const int* in_sizes, int n_in,
                              void* d_out, int out_size, void* d_ws, size_t ws_size,
                              hipStream_t stream) {
  (void)in_sizes; (void)n_in; (void)out_size; (void)ws_size;
  const float* x     = (const float*)d_in[0];
  const float* wh1   = (const float*)d_in[1];
  const float* wh2   = (const float*)d_in[2];
  const float* wv1   = (const float*)d_in[3];
  const float* wv2   = (const float*)d_in[4];
  const float* wproj = (const float*)d_in[5];
  float* out = (float*)d_out;

  // ws layout: Ap (512 KB) | wt2 (36 KB)
  char* wsb = (char*)d_ws;
  unsigned short* Ap = (unsigned short*)wsb;
  float* Wt2         = (float*)(wsb + (size_t)CC * KDIM * 2);

  hipLaunchKernelGGL(prep_kernel, dim3(1024), dim3(256), 0, stream, wproj, Ap);
  hipLaunchKernelGGL(wprep_kernel, dim3(36), dim3(256), 0, stream,
                     wh1, wh2, wv1, wv2, Wt2);
  hipLaunchKernelGGL(fused_kernel, dim3(1024), dim3(512), 0, stream,
                     Ap, x, Wt2, out);
}